// Round 18
// baseline (554.308 us; speedup 1.0000x reference)
//
#include <hip/hip_runtime.h>
#include <cstdint>
#include <cstddef>

// ---------- problem constants ----------
#define DIM      1024
#define GROUP    16
#define LORA     20
#define NLAYERS  18
#define NBLOCKS  6
#define BATCH    8192
#define EPS      1e-5f

typedef __bf16 bf16_8 __attribute__((ext_vector_type(8)));
typedef __bf16 bf16_4 __attribute__((ext_vector_type(4)));
typedef float  f32x4  __attribute__((ext_vector_type(4)));

// ---------------------------------------------------------------------------
// Weight prep: W = qw*scale + B@A -> single bf16.  R15 structure, with the
// qw/scale global loads HOISTED above the LDS staging (their ~900cyc HBM
// latency overlaps the As/Bs staging + barrier instead of stalling the
// j-loop start).  bounds (256,3): VGPR cap ~170, no spill (LDS-As form).
// ---------------------------------------------------------------------------
__global__ __launch_bounds__(256, 3) void wprep_kernel(
    const int* __restrict__ qw, const float* __restrict__ sc,
    const float* __restrict__ la, const float* __restrict__ lb,
    __bf16* __restrict__ whi) {
  const int l  = blockIdx.x >> 7;
  const int og = (blockIdx.x >> 1) & 63;
  const int cg = blockIdx.x & 1;
  const int tid = threadIdx.x;
  const int tc = tid & 31;
  const int tr = tid >> 5;

  // ---- hoisted global loads (in flight during staging) ----
  int4  q[2][4];
  float sv[2][4];
  size_t rowb[2];
#pragma unroll
  for (int u = 0; u < 2; ++u) {
    const int orow = og * 16 + tr * 2 + u;
    rowb[u] = ((size_t)l * DIM + orow) * DIM + cg * 512;
    const size_t scb = ((size_t)l * DIM + orow) * (DIM / GROUP) + cg * 32;
#pragma unroll
    for (int v = 0; v < 4; ++v) {
      const int c = v * 128 + tc * 4;
      q[u][v] = *(const int4*)&qw[rowb[u] + c];
      sv[u][v] = sc[scb + (c >> 4)];
    }
  }

  __shared__ float As[10 * 512];           // 20 KB (half of A's rows)
  __shared__ float Bs[16 * LORA];          // 1.25 KB

  const float* Abase = la + (size_t)l * LORA * DIM + cg * 512;
  const float* Bbase = lb + ((size_t)l * DIM + og * 16) * LORA;
  for (int i = tid; i < 16 * LORA; i += 256) Bs[i] = Bbase[i];
#pragma unroll
  for (int i = 0; i < 5; ++i) {            // stage A rows 0..9
    const int f4 = i * 256 + tid;
    ((float4*)As)[f4] = *(const float4*)(Abase + (size_t)(f4 >> 7) * DIM + (f4 & 127) * 4);
  }
  __syncthreads();

  float acc[2][16];
#pragma unroll
  for (int u = 0; u < 2; ++u)
#pragma unroll
    for (int v = 0; v < 4; ++v) {
      acc[u][v * 4 + 0] = q[u][v].x * sv[u][v];
      acc[u][v * 4 + 1] = q[u][v].y * sv[u][v];
      acc[u][v * 4 + 2] = q[u][v].z * sv[u][v];
      acc[u][v * 4 + 3] = q[u][v].w * sv[u][v];
    }

#pragma unroll 1
  for (int half = 0; half < 2; ++half) {
    if (half == 1) {
      __syncthreads();
#pragma unroll
      for (int i = 0; i < 5; ++i) {        // stage A rows 10..19
        const int f4 = i * 256 + tid;
        ((float4*)As)[f4] =
            *(const float4*)(Abase + (size_t)(10 + (f4 >> 7)) * DIM + (f4 & 127) * 4);
      }
      __syncthreads();
    }
#pragma unroll 2
    for (int jj = 0; jj < 10; ++jj) {
      const int j = half * 10 + jj;
      float4 a[4];
#pragma unroll
      for (int v = 0; v < 4; ++v)
        a[v] = *(const float4*)&As[jj * 512 + v * 128 + tc * 4];  // 16B lane stride
#pragma unroll
      for (int u = 0; u < 2; ++u) {
        const float bj = Bs[(tr * 2 + u) * LORA + j];
#pragma unroll
        for (int v = 0; v < 4; ++v) {
          acc[u][v * 4 + 0] += bj * a[v].x;
          acc[u][v * 4 + 1] += bj * a[v].y;
          acc[u][v * 4 + 2] += bj * a[v].z;
          acc[u][v * 4 + 3] += bj * a[v].w;
        }
      }
    }
  }

#pragma unroll
  for (int u = 0; u < 2; ++u) {
#pragma unroll
    for (int v = 0; v < 4; ++v) {
      const bf16_4 hv = {(__bf16)acc[u][v * 4 + 0], (__bf16)acc[u][v * 4 + 1],
                         (__bf16)acc[u][v * 4 + 2], (__bf16)acc[u][v * 4 + 3]};
      *(bf16_4*)&whi[rowb[u] + v * 128 + tc * 4] = hv;
    }
  }
}

// ---------------------------------------------------------------------------
// x prep: f32 -> single bf16
// ---------------------------------------------------------------------------
__global__ __launch_bounds__(256) void xprep_kernel(
    const float* __restrict__ x, __bf16* __restrict__ hi) {
  const size_t i = (size_t)blockIdx.x * 256 + threadIdx.x;
  const float4 v = ((const float4*)x)[i];
  const bf16_4 hv = {(__bf16)v.x, (__bf16)v.y, (__bf16)v.z, (__bf16)v.w};
  ((bf16_4*)hi)[i] = hv;
}

// ---------------------------------------------------------------------------
// 1-pass bf16 GEMM — 256x128 tile, BK=32, 512 thr (R15 base; R16's 128²
// regressed).  NEW: 4 x 24KB buffer ring (96 KB), depth-2 prefetch with
// counted vmcnt(6): TWO tiles stay in flight across the barrier, covering
// ~1400cyc of HBM latency (depth-1's 700cyc K-step left a residual stall).
// Epilogue MODE: 0 = relu->bf16; 1 = +x residual -> f32 (block 0);
// 2 = +LN(Sprev) recomputed from per-row stats (Hb never materialized).
// ---------------------------------------------------------------------------
#define GBUF    12288   // elems per buffer (24 KB)
#define GOFF_W  8192    // X 256x32 first, then W 128x32

template <int NISSUE>
__device__ __forceinline__ void stageR(const __bf16* __restrict__ g, int row0, int k0,
                                       __bf16* lds, int tid) {
#pragma unroll
  for (int i = 0; i < NISSUE; ++i) {
    const int D = i * 8192 + tid * 16;
    const int r  = D >> 6;                 // 64 B per row (BK=32 bf16)
    const int ce = (D & 63) >> 1;
    const __bf16* gp = g + (size_t)(row0 + r) * DIM + k0 + ce;
    __builtin_amdgcn_global_load_lds(
        (const __attribute__((address_space(1))) void*)gp,
        (__attribute__((address_space(3))) void*)(lds + i * 4096 + (tid >> 6) * 512), 16, 0, 0);
  }
}

template <int MODE>
__global__ __launch_bounds__(512, 1) void gemm1_kernel(
    const __bf16* __restrict__ X, const __bf16* __restrict__ Wh,
    const float* __restrict__ bias, __bf16* __restrict__ Oh,
    const float* __restrict__ Hin,          // MODE1: x;  MODE2: Sprev
    const float2* __restrict__ stats,       // MODE2: per-row {mean, inv}
    const float* __restrict__ lnw, const float* __restrict__ lnb,  // MODE2
    float* __restrict__ Sout) {
  __shared__ __bf16 smem[4 * GBUF];        // 96 KB

  const int tid  = threadIdx.x;
  const int lane = tid & 63;
  const int wv   = tid >> 6;
  const int wm   = wv >> 2;
  const int wn2  = wv & 3;
  const int xcd = blockIdx.x & 7;
  const int kk  = blockIdx.x >> 3;
  const int tm  = xcd * 4 + (kk >> 3);
  const int tn  = kk & 7;
  const int rowX = tm * 256, rowW = tn * 128;

  const int lr   = lane & 15;
  const int slot = lane >> 4;

  int offX[4], offW[4];
#pragma unroll
  for (int n = 0; n < 4; ++n) offX[n] = (wn2 * 64 + n * 16 + lr) * 32 + slot * 8;
#pragma unroll
  for (int m = 0; m < 4; ++m) offW[m] = GOFF_W + (wm * 64 + m * 16 + lr) * 32 + slot * 8;

  f32x4 acc[4][4];
#pragma unroll
  for (int m = 0; m < 4; ++m)
#pragma unroll
    for (int n = 0; n < 4; ++n) acc[m][n] = f32x4{0.f, 0.f, 0.f, 0.f};

  auto stage_tile = [&](int t) {
    __bf16* sb = smem + (t & 3) * GBUF;
    stageR<2>(X,  rowX, t * 32, sb, tid);
    stageR<1>(Wh, rowW, t * 32, sb + GOFF_W, tid);
  };

  auto compute_tile = [&](int t) {
    const __bf16* buf = smem + (t & 3) * GBUF;
    bf16_8 xf[4];
#pragma unroll
    for (int n = 0; n < 4; ++n) xf[n] = *(const bf16_8*)&buf[offX[n]];
#pragma unroll
    for (int m = 0; m < 4; ++m) {
      const bf16_8 w_h = *(const bf16_8*)&buf[offW[m]];
#pragma unroll
      for (int n = 0; n < 4; ++n)
        acc[m][n] = __builtin_amdgcn_mfma_f32_16x16x32_bf16(w_h, xf[n], acc[m][n], 0, 0, 0);
    }
  };

  // prologue: tiles 0,1,2 issued (9 loads); vmcnt(6) -> tile 0 landed,
  // tiles 1,2 (6 loads) stay in flight across the barrier.
  stage_tile(0); stage_tile(1); stage_tile(2);
  asm volatile("s_waitcnt vmcnt(6)" ::: "memory");
  __builtin_amdgcn_s_barrier();

#pragma unroll 1
  for (int kt = 0; kt < 29; ++kt) {
    stage_tile(kt + 3);                    // into tile kt-1's buffer (consumed)
    compute_tile(kt);
    // drain tile kt+1's 3 loads (oldest); kt+2, kt+3 (6 newest) stay in flight
    asm volatile("s_waitcnt vmcnt(6)" ::: "memory");
    __builtin_amdgcn_s_barrier();
  }
  compute_tile(29);
  asm volatile("s_waitcnt vmcnt(3)" ::: "memory");   // tile 30 landed
  __builtin_amdgcn_s_barrier();
  compute_tile(30);
  asm volatile("s_waitcnt vmcnt(0)" ::: "memory");   // tile 31 landed
  __builtin_amdgcn_s_barrier();
  compute_tile(31);

  // epilogue: D reg-quad = 4 consecutive features of one batch row
  const int g4 = slot * 4;
#pragma unroll
  for (int m = 0; m < 4; ++m) {
    const int feat = tn * 128 + wm * 64 + m * 16 + g4;
    const float4 bv = *(const float4*)&bias[feat];
    float4 wq, bq;
    if constexpr (MODE == 2) {
      wq = *(const float4*)&lnw[feat];
      bq = *(const float4*)&lnb[feat];
    }
#pragma unroll
    for (int n = 0; n < 4; ++n) {
      const int nb = tm * 256 + wn2 * 64 + n * 16 + lr;
      const size_t base = (size_t)nb * DIM + feat;
      float v0 = acc[m][n][0] + bv.x;
      float v1 = acc[m][n][1] + bv.y;
      float v2 = acc[m][n][2] + bv.z;
      float v3 = acc[m][n][3] + bv.w;
      if constexpr (MODE == 0) {
        const bf16_4 hv = {(__bf16)fmaxf(v0, 0.f), (__bf16)fmaxf(v1, 0.f),
                           (__bf16)fmaxf(v2, 0.f), (__bf16)fmaxf(v3, 0.f)};
        *(bf16_4*)&Oh[base] = hv;
      } else if constexpr (MODE == 1) {
        const float4 h = *(const float4*)&Hin[base];
        *(float4*)&Sout[base] = float4{v0 + h.x, v1 + h.y, v2 + h.z, v3 + h.w};
      } else {
        const float2 st = stats[nb];                   // {mean, inv}
        const float4 s = *(const float4*)&Hin[base];   // Sprev
        const float h0 = (s.x - st.x) * st.y * wq.x + bq.x;
        const float h1 = (s.y - st.x) * st.y * wq.y + bq.y;
        const float h2 = (s.z - st.x) * st.y * wq.z + bq.z;
        const float h3 = (s.w - st.x) * st.y * wq.w + bq.w;
        *(float4*)&Sout[base] = float4{v0 + h0, v1 + h1, v2 + h2, v3 + h3};
      }
    }
  }
}

// ---------------------------------------------------------------------------
// normcast: per-row stats {mean, inv} + bf16 LN output (next block's X).
// ---------------------------------------------------------------------------
__global__ __launch_bounds__(256) void normcast_kernel(
    const float* __restrict__ S, const float* __restrict__ w,
    const float* __restrict__ b, float2* __restrict__ stats,
    __bf16* __restrict__ phi) {
  const int row = blockIdx.x;
  const int tid = threadIdx.x;
  const int lane = tid & 63;
  const int wv = tid >> 6;
  const float4 v = ((const float4*)(S + (size_t)row * DIM))[tid];

  float s = v.x + v.y + v.z + v.w;
#pragma unroll
  for (int m = 32; m; m >>= 1) s += __shfl_xor(s, m, 64);
  __shared__ float red[8];
  if (lane == 0) red[wv] = s;
  __syncthreads();
  const float mean = (red[0] + red[1] + red[2] + red[3]) * (1.f / DIM);

  const float d0 = v.x - mean, d1 = v.y - mean, d2 = v.z - mean, d3 = v.w - mean;
  float q = d0 * d0 + d1 * d1 + d2 * d2 + d3 * d3;
#pragma unroll
  for (int m = 32; m; m >>= 1) q += __shfl_xor(q, m, 64);
  if (lane == 0) red[4 + wv] = q;
  __syncthreads();
  const float var = (red[4] + red[5] + red[6] + red[7]) * (1.f / DIM);
  const float inv = 1.f / sqrtf(var + EPS);

  if (tid == 0) stats[row] = float2{mean, inv};

  const float4 wv4 = ((const float4*)w)[tid];
  const float4 bv4 = ((const float4*)b)[tid];
  const bf16_4 hv = {(__bf16)(d0 * inv * wv4.x + bv4.x),
                     (__bf16)(d1 * inv * wv4.y + bv4.y),
                     (__bf16)(d2 * inv * wv4.z + bv4.z),
                     (__bf16)(d3 * inv * wv4.w + bv4.w)};
  ((bf16_4*)phi)[(size_t)row * (DIM / 4) + tid] = hv;
}

// ---------------------------------------------------------------------------
// launch
// ---------------------------------------------------------------------------
extern "C" void kernel_launch(void* const* d_in, const int* in_sizes, int n_in,
                              void* d_out, int out_size, void* d_ws, size_t ws_size,
                              hipStream_t stream) {
  const float* x   = (const float*)d_in[0];
  const int*   qw  = (const int*)d_in[1];
  const float* sc  = (const float*)d_in[2];
  const float* bias= (const float*)d_in[3];
  const float* la  = (const float*)d_in[4];
  const float* lb  = (const float*)d_in[5];
  const float* lnw = (const float*)d_in[6];
  const float* lnb = (const float*)d_in[7];
  float* out = (float*)d_out;
  char* ws = (char*)d_ws;

  // ws layout (bytes): WHI 36M | X0 16M | X1 16M | SA 32M | SB 32M | stats 64K
  __bf16* WHI = (__bf16*)(ws);
  __bf16* X0  = (__bf16*)(ws + 37748736);
  __bf16* X1  = (__bf16*)(ws + 54525952);
  float*  SA  = (float*)(ws + 71303168);
  float*  SB  = (float*)(ws + 104857600);
  float2* STT = (float2*)(ws + 138412032);
  (void)ws_size; (void)in_sizes; (void)n_in; (void)out_size;

  xprep_kernel<<<BATCH * DIM / (256 * 4), 256, 0, stream>>>(x, X0);
  wprep_kernel<<<NLAYERS * 128, 256, 0, stream>>>(qw, sc, la, lb, WHI);

  const dim3 ggrid(BATCH / 256 * (DIM / 128));          // 256 = 1 block/CU
  for (int blk = 0; blk < NBLOCKS; ++blk) {
    const int li = blk * 3;
    const size_t w0 = (size_t)li * DIM * DIM;
    const size_t w1 = (size_t)(li + 1) * DIM * DIM;
    const size_t w2 = (size_t)(li + 2) * DIM * DIM;
    float* Scur = (blk & 1) ? SB : SA;
    float* Sprev = (blk & 1) ? SA : SB;

    gemm1_kernel<0><<<ggrid, 512, 0, stream>>>(
        X0, WHI + w0, bias + (size_t)li * DIM, X1,
        nullptr, nullptr, nullptr, nullptr, nullptr);
    gemm1_kernel<0><<<ggrid, 512, 0, stream>>>(
        X1, WHI + w1, bias + (size_t)(li + 1) * DIM, X0,
        nullptr, nullptr, nullptr, nullptr, nullptr);
    float* sout = (blk == NBLOCKS - 1) ? out : Scur;
    if (blk == 0) {
      gemm1_kernel<1><<<ggrid, 512, 0, stream>>>(
          X0, WHI + w2, bias + (size_t)(li + 2) * DIM, nullptr,
          x, nullptr, nullptr, nullptr, sout);
    } else {
      gemm1_kernel<2><<<ggrid, 512, 0, stream>>>(
          X0, WHI + w2, bias + (size_t)(li + 2) * DIM, nullptr,
          Sprev, STT, lnw + (size_t)(blk - 1) * DIM, lnb + (size_t)(blk - 1) * DIM,
          sout);
    }
    if (blk < NBLOCKS - 1) {
      normcast_kernel<<<BATCH, 256, 0, stream>>>(
          Scur, lnw + (size_t)blk * DIM, lnb + (size_t)blk * DIM, STT, X0);
    }
  }
}

// Round 19
// 527.810 us; speedup vs baseline: 1.0502x; 1.0502x over previous
//
#include <hip/hip_runtime.h>
#include <cstdint>
#include <cstddef>

// ---------- problem constants ----------
#define DIM      1024
#define GROUP    16
#define LORA     20
#define NLAYERS  18
#define NBLOCKS  6
#define BATCH    8192
#define EPS      1e-5f

typedef __bf16 bf16_8 __attribute__((ext_vector_type(8)));
typedef __bf16 bf16_4 __attribute__((ext_vector_type(4)));
typedef float  f32x4  __attribute__((ext_vector_type(4)));

// ---------------------------------------------------------------------------
// Weight prep (R17, unchanged): W = qw*scale + B@A -> single bf16.
// ---------------------------------------------------------------------------
__global__ __launch_bounds__(256, 3) void wprep_kernel(
    const int* __restrict__ qw, const float* __restrict__ sc,
    const float* __restrict__ la, const float* __restrict__ lb,
    __bf16* __restrict__ whi) {
  const int l  = blockIdx.x >> 7;
  const int og = (blockIdx.x >> 1) & 63;
  const int cg = blockIdx.x & 1;
  const int tid = threadIdx.x;
  const int tc = tid & 31;
  const int tr = tid >> 5;

  int4  q[2][4];
  float sv[2][4];
  size_t rowb[2];
#pragma unroll
  for (int u = 0; u < 2; ++u) {
    const int orow = og * 16 + tr * 2 + u;
    rowb[u] = ((size_t)l * DIM + orow) * DIM + cg * 512;
    const size_t scb = ((size_t)l * DIM + orow) * (DIM / GROUP) + cg * 32;
#pragma unroll
    for (int v = 0; v < 4; ++v) {
      const int c = v * 128 + tc * 4;
      q[u][v] = *(const int4*)&qw[rowb[u] + c];
      sv[u][v] = sc[scb + (c >> 4)];
    }
  }

  __shared__ float As[10 * 512];
  __shared__ float Bs[16 * LORA];

  const float* Abase = la + (size_t)l * LORA * DIM + cg * 512;
  const float* Bbase = lb + ((size_t)l * DIM + og * 16) * LORA;
  for (int i = tid; i < 16 * LORA; i += 256) Bs[i] = Bbase[i];
#pragma unroll
  for (int i = 0; i < 5; ++i) {
    const int f4 = i * 256 + tid;
    ((float4*)As)[f4] = *(const float4*)(Abase + (size_t)(f4 >> 7) * DIM + (f4 & 127) * 4);
  }
  __syncthreads();

  float acc[2][16];
#pragma unroll
  for (int u = 0; u < 2; ++u)
#pragma unroll
    for (int v = 0; v < 4; ++v) {
      acc[u][v * 4 + 0] = q[u][v].x * sv[u][v];
      acc[u][v * 4 + 1] = q[u][v].y * sv[u][v];
      acc[u][v * 4 + 2] = q[u][v].z * sv[u][v];
      acc[u][v * 4 + 3] = q[u][v].w * sv[u][v];
    }

#pragma unroll 1
  for (int half = 0; half < 2; ++half) {
    if (half == 1) {
      __syncthreads();
#pragma unroll
      for (int i = 0; i < 5; ++i) {
        const int f4 = i * 256 + tid;
        ((float4*)As)[f4] =
            *(const float4*)(Abase + (size_t)(10 + (f4 >> 7)) * DIM + (f4 & 127) * 4);
      }
      __syncthreads();
    }
#pragma unroll 2
    for (int jj = 0; jj < 10; ++jj) {
      const int j = half * 10 + jj;
      float4 a[4];
#pragma unroll
      for (int v = 0; v < 4; ++v)
        a[v] = *(const float4*)&As[jj * 512 + v * 128 + tc * 4];
#pragma unroll
      for (int u = 0; u < 2; ++u) {
        const float bj = Bs[(tr * 2 + u) * LORA + j];
#pragma unroll
        for (int v = 0; v < 4; ++v) {
          acc[u][v * 4 + 0] += bj * a[v].x;
          acc[u][v * 4 + 1] += bj * a[v].y;
          acc[u][v * 4 + 2] += bj * a[v].z;
          acc[u][v * 4 + 3] += bj * a[v].w;
        }
      }
    }
  }

#pragma unroll
  for (int u = 0; u < 2; ++u) {
#pragma unroll
    for (int v = 0; v < 4; ++v) {
      const bf16_4 hv = {(__bf16)acc[u][v * 4 + 0], (__bf16)acc[u][v * 4 + 1],
                         (__bf16)acc[u][v * 4 + 2], (__bf16)acc[u][v * 4 + 3]};
      *(bf16_4*)&whi[rowb[u] + v * 128 + tc * 4] = hv;
    }
  }
}

// ---------------------------------------------------------------------------
// x prep: f32 -> single bf16
// ---------------------------------------------------------------------------
__global__ __launch_bounds__(256) void xprep_kernel(
    const float* __restrict__ x, __bf16* __restrict__ hi) {
  const size_t i = (size_t)blockIdx.x * 256 + threadIdx.x;
  const float4 v = ((const float4*)x)[i];
  const bf16_4 hv = {(__bf16)v.x, (__bf16)v.y, (__bf16)v.z, (__bf16)v.w};
  ((bf16_4*)hi)[i] = hv;
}

// ---------------------------------------------------------------------------
// 1-pass bf16 GEMM — 256x128 tile, BK=64, 512 thr.
// BK=64: 16 K-steps instead of 32 -> halves per-step fixed costs (barrier
// skew, waitcnt checks) which R17's model showed dominate (1700cyc/step vs
// ~500 of flow).  Occupancy unchanged (3 x 48KB = 144KB, was already
// 1 block/CU).  Rows are now 128B = the 32-way-conflict pathology (G4), so
// T2 XOR swizzle applies: frag-read byte ^= (row&7)<<4, with the INVERSE
// involution on the global_load_lds SOURCE address (rule #21; linear LDS
// dest).  16-lane frag group then spreads over 8x16B slots = free 2-way.
// 3-buffer ring, 2 tiles in flight, vmcnt(6) (6 loads/tile).
// Epilogue MODE: 0 = relu->bf16; 1 = +x residual; 2 = +LN(Sprev) from stats.
// ---------------------------------------------------------------------------
#define GBUF    24576   // elems per buffer (48 KB)
#define GOFF_W  16384   // X 256x64 elems first, then W 128x64

__device__ __forceinline__ int swz_off(int row, int slot) {
  const int colb = (slot * 16) ^ ((row & 7) << 4);
  return (row * 128 + colb) >> 1;   // elem offset
}

template <int NISSUE>
__device__ __forceinline__ void stageR(const __bf16* __restrict__ g, int row0, int k0,
                                       __bf16* lds, int tid) {
#pragma unroll
  for (int i = 0; i < NISSUE; ++i) {
    const int D = i * 8192 + tid * 16;     // linear LDS byte in region
    const int row = D >> 7;                // 128 B per row (BK=64 bf16)
    const int colb = (D & 127) ^ ((row & 7) << 4);   // inverse swizzle on src
    const __bf16* gp = g + (size_t)(row0 + row) * DIM + k0 + (colb >> 1);
    __builtin_amdgcn_global_load_lds(
        (const __attribute__((address_space(1))) void*)gp,
        (__attribute__((address_space(3))) void*)(lds + i * 4096 + (tid >> 6) * 512), 16, 0, 0);
  }
}

template <int MODE>
__global__ __launch_bounds__(512, 1) void gemm1_kernel(
    const __bf16* __restrict__ X, const __bf16* __restrict__ Wh,
    const float* __restrict__ bias, __bf16* __restrict__ Oh,
    const float* __restrict__ Hin,          // MODE1: x;  MODE2: Sprev
    const float2* __restrict__ stats,       // MODE2: per-row {mean, inv}
    const float* __restrict__ lnw, const float* __restrict__ lnb,  // MODE2
    float* __restrict__ Sout) {
  __shared__ __bf16 smem[3 * GBUF];        // 144 KB

  const int tid  = threadIdx.x;
  const int lane = tid & 63;
  const int wv   = tid >> 6;
  const int wm   = wv >> 2;
  const int wn2  = wv & 3;
  const int xcd = blockIdx.x & 7;
  const int kk2 = blockIdx.x >> 3;
  const int tm  = xcd * 4 + (kk2 >> 3);
  const int tn  = kk2 & 7;
  const int rowX = tm * 256, rowW = tn * 128;

  const int lr   = lane & 15;
  const int slot = lane >> 4;

  int offX[4], offW[4];
#pragma unroll
  for (int n = 0; n < 4; ++n) offX[n] = swz_off(wn2 * 64 + n * 16 + lr, slot);
#pragma unroll
  for (int m = 0; m < 4; ++m) offW[m] = GOFF_W + swz_off(wm * 64 + m * 16 + lr, slot);

  f32x4 acc[4][4];
#pragma unroll
  for (int m = 0; m < 4; ++m)
#pragma unroll
    for (int n = 0; n < 4; ++n) acc[m][n] = f32x4{0.f, 0.f, 0.f, 0.f};

  auto stage_tile = [&](int t) {
    __bf16* sb = smem + (t % 3) * GBUF;
    stageR<4>(X,  rowX, t * 64, sb, tid);
    stageR<2>(Wh, rowW, t * 64, sb + GOFF_W, tid);
  };

  auto compute_tile = [&](int t) {
    const __bf16* buf = smem + (t % 3) * GBUF;
#pragma unroll
    for (int kk = 0; kk < 2; ++kk) {
      const int kx = kk * 32;              // elem-offset XOR delta (byte 64)
      bf16_8 xf[4];
#pragma unroll
      for (int n = 0; n < 4; ++n) xf[n] = *(const bf16_8*)&buf[offX[n] ^ kx];
#pragma unroll
      for (int m = 0; m < 4; ++m) {
        const bf16_8 w_h = *(const bf16_8*)&buf[offW[m] ^ kx];
#pragma unroll
        for (int n = 0; n < 4; ++n)
          acc[m][n] = __builtin_amdgcn_mfma_f32_16x16x32_bf16(w_h, xf[n], acc[m][n], 0, 0, 0);
      }
    }
  };

  // prologue: tiles 0,1 issued (12 loads); vmcnt(6) -> tile 0 landed,
  // tile 1's 6 loads stay in flight across the barrier.
  stage_tile(0); stage_tile(1);
  asm volatile("s_waitcnt vmcnt(6)" ::: "memory");
  __builtin_amdgcn_s_barrier();

#pragma unroll 1
  for (int kt = 0; kt < 14; ++kt) {
    stage_tile(kt + 2);                    // into tile kt-1's buffer (consumed)
    compute_tile(kt);
    // drain tile kt+1's 6 loads (oldest); kt+2's 6 newest stay in flight
    asm volatile("s_waitcnt vmcnt(6)" ::: "memory");
    __builtin_amdgcn_s_barrier();
  }
  compute_tile(14);
  asm volatile("s_waitcnt vmcnt(0)" ::: "memory");
  __builtin_amdgcn_s_barrier();
  compute_tile(15);

  // epilogue: D reg-quad = 4 consecutive features of one batch row
  const int g4 = slot * 4;
#pragma unroll
  for (int m = 0; m < 4; ++m) {
    const int feat = tn * 128 + wm * 64 + m * 16 + g4;
    const float4 bv = *(const float4*)&bias[feat];
    float4 wq, bq;
    if constexpr (MODE == 2) {
      wq = *(const float4*)&lnw[feat];
      bq = *(const float4*)&lnb[feat];
    }
#pragma unroll
    for (int n = 0; n < 4; ++n) {
      const int nb = tm * 256 + wn2 * 64 + n * 16 + lr;
      const size_t base = (size_t)nb * DIM + feat;
      float v0 = acc[m][n][0] + bv.x;
      float v1 = acc[m][n][1] + bv.y;
      float v2 = acc[m][n][2] + bv.z;
      float v3 = acc[m][n][3] + bv.w;
      if constexpr (MODE == 0) {
        const bf16_4 hv = {(__bf16)fmaxf(v0, 0.f), (__bf16)fmaxf(v1, 0.f),
                           (__bf16)fmaxf(v2, 0.f), (__bf16)fmaxf(v3, 0.f)};
        *(bf16_4*)&Oh[base] = hv;
      } else if constexpr (MODE == 1) {
        const float4 h = *(const float4*)&Hin[base];
        *(float4*)&Sout[base] = float4{v0 + h.x, v1 + h.y, v2 + h.z, v3 + h.w};
      } else {
        const float2 st = stats[nb];                   // {mean, inv}
        const float4 s = *(const float4*)&Hin[base];   // Sprev
        const float h0 = (s.x - st.x) * st.y * wq.x + bq.x;
        const float h1 = (s.y - st.x) * st.y * wq.y + bq.y;
        const float h2 = (s.z - st.x) * st.y * wq.z + bq.z;
        const float h3 = (s.w - st.x) * st.y * wq.w + bq.w;
        *(float4*)&Sout[base] = float4{v0 + h0, v1 + h1, v2 + h2, v3 + h3};
      }
    }
  }
}

// ---------------------------------------------------------------------------
// normcast: per-row stats {mean, inv} + bf16 LN output (next block's X).
// ---------------------------------------------------------------------------
__global__ __launch_bounds__(256) void normcast_kernel(
    const float* __restrict__ S, const float* __restrict__ w,
    const float* __restrict__ b, float2* __restrict__ stats,
    __bf16* __restrict__ phi) {
  const int row = blockIdx.x;
  const int tid = threadIdx.x;
  const int lane = tid & 63;
  const int wv = tid >> 6;
  const float4 v = ((const float4*)(S + (size_t)row * DIM))[tid];

  float s = v.x + v.y + v.z + v.w;
#pragma unroll
  for (int m = 32; m; m >>= 1) s += __shfl_xor(s, m, 64);
  __shared__ float red[8];
  if (lane == 0) red[wv] = s;
  __syncthreads();
  const float mean = (red[0] + red[1] + red[2] + red[3]) * (1.f / DIM);

  const float d0 = v.x - mean, d1 = v.y - mean, d2 = v.z - mean, d3 = v.w - mean;
  float q = d0 * d0 + d1 * d1 + d2 * d2 + d3 * d3;
#pragma unroll
  for (int m = 32; m; m >>= 1) q += __shfl_xor(q, m, 64);
  if (lane == 0) red[4 + wv] = q;
  __syncthreads();
  const float var = (red[4] + red[5] + red[6] + red[7]) * (1.f / DIM);
  const float inv = 1.f / sqrtf(var + EPS);

  if (tid == 0) stats[row] = float2{mean, inv};

  const float4 wv4 = ((const float4*)w)[tid];
  const float4 bv4 = ((const float4*)b)[tid];
  const bf16_4 hv = {(__bf16)(d0 * inv * wv4.x + bv4.x),
                     (__bf16)(d1 * inv * wv4.y + bv4.y),
                     (__bf16)(d2 * inv * wv4.z + bv4.z),
                     (__bf16)(d3 * inv * wv4.w + bv4.w)};
  ((bf16_4*)phi)[(size_t)row * (DIM / 4) + tid] = hv;
}

// ---------------------------------------------------------------------------
// launch
// ---------------------------------------------------------------------------
extern "C" void kernel_launch(void* const* d_in, const int* in_sizes, int n_in,
                              void* d_out, int out_size, void* d_ws, size_t ws_size,
                              hipStream_t stream) {
  const float* x   = (const float*)d_in[0];
  const int*   qw  = (const int*)d_in[1];
  const float* sc  = (const float*)d_in[2];
  const float* bias= (const float*)d_in[3];
  const float* la  = (const float*)d_in[4];
  const float* lb  = (const float*)d_in[5];
  const float* lnw = (const float*)d_in[6];
  const float* lnb = (const float*)d_in[7];
  float* out = (float*)d_out;
  char* ws = (char*)d_ws;

  // ws layout (bytes): WHI 36M | X0 16M | X1 16M | SA 32M | SB 32M | stats 64K
  __bf16* WHI = (__bf16*)(ws);
  __bf16* X0  = (__bf16*)(ws + 37748736);
  __bf16* X1  = (__bf16*)(ws + 54525952);
  float*  SA  = (float*)(ws + 71303168);
  float*  SB  = (float*)(ws + 104857600);
  float2* STT = (float2*)(ws + 138412032);
  (void)ws_size; (void)in_sizes; (void)n_in; (void)out_size;

  xprep_kernel<<<BATCH * DIM / (256 * 4), 256, 0, stream>>>(x, X0);
  wprep_kernel<<<NLAYERS * 128, 256, 0, stream>>>(qw, sc, la, lb, WHI);

  const dim3 ggrid(BATCH / 256 * (DIM / 128));          // 256 = 1 block/CU
  for (int blk = 0; blk < NBLOCKS; ++blk) {
    const int li = blk * 3;
    const size_t w0 = (size_t)li * DIM * DIM;
    const size_t w1 = (size_t)(li + 1) * DIM * DIM;
    const size_t w2 = (size_t)(li + 2) * DIM * DIM;
    float* Scur = (blk & 1) ? SB : SA;
    float* Sprev = (blk & 1) ? SA : SB;

    gemm1_kernel<0><<<ggrid, 512, 0, stream>>>(
        X0, WHI + w0, bias + (size_t)li * DIM, X1,
        nullptr, nullptr, nullptr, nullptr, nullptr);
    gemm1_kernel<0><<<ggrid, 512, 0, stream>>>(
        X1, WHI + w1, bias + (size_t)(li + 1) * DIM, X0,
        nullptr, nullptr, nullptr, nullptr, nullptr);
    float* sout = (blk == NBLOCKS - 1) ? out : Scur;
    if (blk == 0) {
      gemm1_kernel<1><<<ggrid, 512, 0, stream>>>(
          X0, WHI + w2, bias + (size_t)(li + 2) * DIM, nullptr,
          x, nullptr, nullptr, nullptr, sout);
    } else {
      gemm1_kernel<2><<<ggrid, 512, 0, stream>>>(
          X0, WHI + w2, bias + (size_t)(li + 2) * DIM, nullptr,
          Sprev, STT, lnw + (size_t)(blk - 1) * DIM, lnb + (size_t)(blk - 1) * DIM,
          sout);
    }
    if (blk < NBLOCKS - 1) {
      normcast_kernel<<<BATCH, 256, 0, stream>>>(
          Scur, lnw + (size_t)blk * DIM, lnb + (size_t)blk * DIM, STT, X0);
    }
  }
}

// Round 20
// 525.141 us; speedup vs baseline: 1.0555x; 1.0051x over previous
//
#include <hip/hip_runtime.h>
#include <cstdint>
#include <cstddef>

// ---------- problem constants ----------
#define DIM      1024
#define GROUP    16
#define LORA     20
#define NLAYERS  18
#define NBLOCKS  6
#define BATCH    8192
#define EPS      1e-5f

typedef __bf16 bf16_8 __attribute__((ext_vector_type(8)));
typedef __bf16 bf16_4 __attribute__((ext_vector_type(4)));
typedef float  f32x4  __attribute__((ext_vector_type(4)));

// ---------------------------------------------------------------------------
// Weight prep: W = qw*scale + B@A -> single bf16.
// R20: As stored as BF16 [20][512] (20KB, all rows -> no mid-loop restage) and
// thread = 2 rows x 2 chunks of 8 CONSECUTIVE cols -> j-loop reads 2 x b128
// (was 4): halves the LDS-port flow that serializes the 7 resident blocks/CU.
// A-term bf16 rounding ~6e-6 abs — invisible vs the 0.117 budget.
// ---------------------------------------------------------------------------
__global__ __launch_bounds__(256, 3) void wprep_kernel(
    const int* __restrict__ qw, const float* __restrict__ sc,
    const float* __restrict__ la, const float* __restrict__ lb,
    __bf16* __restrict__ whi) {
  const int l  = blockIdx.x >> 7;          // 18 layers x 128 blocks
  const int og = (blockIdx.x >> 1) & 63;   // 64 row-groups of 16
  const int cg = blockIdx.x & 1;           // 2 col-halves of 512
  const int tid = threadIdx.x;
  const int tc = tid & 31;                 // 32 col-chunks of 8 (x2 halves)
  const int tr = tid >> 5;                 // 8 row-pairs

  // ---- hoisted global loads (in flight during staging) ----
  // cols for chunk v: v*256 + tc*8 .. +7  (one 16-group scale per chunk? no:
  // tc*8 is 8-aligned -> spans ONE group iff (tc*8)%16==0 else the upper half
  // of a group; either way all 8 cols share sc index ((v*256+tc*8)>>4)).
  int4  q[2][2][2];                        // [row u][chunk v][lo/hi int4]
  float sv[2][2];
  size_t rowb[2];
#pragma unroll
  for (int u = 0; u < 2; ++u) {
    const int orow = og * 16 + tr * 2 + u;
    rowb[u] = ((size_t)l * DIM + orow) * DIM + cg * 512;
    const size_t scb = ((size_t)l * DIM + orow) * (DIM / GROUP) + cg * 32;
#pragma unroll
    for (int v = 0; v < 2; ++v) {
      const int c = v * 256 + tc * 8;
      q[u][v][0] = *(const int4*)&qw[rowb[u] + c];
      q[u][v][1] = *(const int4*)&qw[rowb[u] + c + 4];
      sv[u][v] = sc[scb + (c >> 4)];
    }
  }

  __shared__ __bf16 As[LORA * 512];        // 20 KB, bf16, ALL 20 rows
  __shared__ float  Bs[16 * LORA];         // 1.25 KB

  const float* Abase = la + (size_t)l * LORA * DIM + cg * 512;
  const float* Bbase = lb + ((size_t)l * DIM + og * 16) * LORA;
  for (int i = tid; i < 16 * LORA; i += 256) Bs[i] = Bbase[i];
#pragma unroll
  for (int i = 0; i < 10; ++i) {           // 10240 elems / (256 thr x 4)
    const int f4 = i * 256 + tid;          // group of 4 floats
    const float4 a = *(const float4*)(Abase + (size_t)(f4 >> 7) * DIM + (f4 & 127) * 4);
    const bf16_4 ab = {(__bf16)a.x, (__bf16)a.y, (__bf16)a.z, (__bf16)a.w};
    *(bf16_4*)&As[f4 * 4] = ab;
  }
  __syncthreads();

  float acc[2][16];                        // [u][v*8+e]
#pragma unroll
  for (int u = 0; u < 2; ++u)
#pragma unroll
    for (int v = 0; v < 2; ++v) {
      acc[u][v * 8 + 0] = q[u][v][0].x * sv[u][v];
      acc[u][v * 8 + 1] = q[u][v][0].y * sv[u][v];
      acc[u][v * 8 + 2] = q[u][v][0].z * sv[u][v];
      acc[u][v * 8 + 3] = q[u][v][0].w * sv[u][v];
      acc[u][v * 8 + 4] = q[u][v][1].x * sv[u][v];
      acc[u][v * 8 + 5] = q[u][v][1].y * sv[u][v];
      acc[u][v * 8 + 6] = q[u][v][1].z * sv[u][v];
      acc[u][v * 8 + 7] = q[u][v][1].w * sv[u][v];
    }

#pragma unroll 2
  for (int j = 0; j < LORA; ++j) {
    float af[2][8];
#pragma unroll
    for (int v = 0; v < 2; ++v) {
      const bf16_8 a8 = *(const bf16_8*)&As[j * 512 + v * 256 + tc * 8];  // b128
#pragma unroll
      for (int e = 0; e < 8; ++e) af[v][e] = (float)a8[e];
    }
#pragma unroll
    for (int u = 0; u < 2; ++u) {
      const float bj = Bs[(tr * 2 + u) * LORA + j];
#pragma unroll
      for (int v = 0; v < 2; ++v)
#pragma unroll
        for (int e = 0; e < 8; ++e) acc[u][v * 8 + e] += bj * af[v][e];
    }
  }

#pragma unroll
  for (int u = 0; u < 2; ++u) {
#pragma unroll
    for (int v = 0; v < 2; ++v) {
      bf16_8 hv;
#pragma unroll
      for (int e = 0; e < 8; ++e) hv[e] = (__bf16)acc[u][v * 8 + e];
      *(bf16_8*)&whi[rowb[u] + v * 256 + tc * 8] = hv;   // 16B store
    }
  }
}

// ---------------------------------------------------------------------------
// x prep: f32 -> single bf16
// ---------------------------------------------------------------------------
__global__ __launch_bounds__(256) void xprep_kernel(
    const float* __restrict__ x, __bf16* __restrict__ hi) {
  const size_t i = (size_t)blockIdx.x * 256 + threadIdx.x;
  const float4 v = ((const float4*)x)[i];
  const bf16_4 hv = {(__bf16)v.x, (__bf16)v.y, (__bf16)v.z, (__bf16)v.w};
  ((bf16_4*)hi)[i] = hv;
}

// ---------------------------------------------------------------------------
// 1-pass bf16 GEMM (R19, frozen): 256x128 tile, BK=64, 512 thr, T2 XOR
// swizzle (inverse on global_load_lds source), 3 x 48KB ring, 2 tiles in
// flight, vmcnt(6).  Epilogue MODE: 0 relu->bf16; 1 +x; 2 +LN(Sprev)(stats).
// ---------------------------------------------------------------------------
#define GBUF    24576   // elems per buffer (48 KB)
#define GOFF_W  16384   // X 256x64 elems first, then W 128x64

__device__ __forceinline__ int swz_off(int row, int slot) {
  const int colb = (slot * 16) ^ ((row & 7) << 4);
  return (row * 128 + colb) >> 1;   // elem offset
}

template <int NISSUE>
__device__ __forceinline__ void stageR(const __bf16* __restrict__ g, int row0, int k0,
                                       __bf16* lds, int tid) {
#pragma unroll
  for (int i = 0; i < NISSUE; ++i) {
    const int D = i * 8192 + tid * 16;     // linear LDS byte in region
    const int row = D >> 7;                // 128 B per row (BK=64 bf16)
    const int colb = (D & 127) ^ ((row & 7) << 4);   // inverse swizzle on src
    const __bf16* gp = g + (size_t)(row0 + row) * DIM + k0 + (colb >> 1);
    __builtin_amdgcn_global_load_lds(
        (const __attribute__((address_space(1))) void*)gp,
        (__attribute__((address_space(3))) void*)(lds + i * 4096 + (tid >> 6) * 512), 16, 0, 0);
  }
}

template <int MODE>
__global__ __launch_bounds__(512, 1) void gemm1_kernel(
    const __bf16* __restrict__ X, const __bf16* __restrict__ Wh,
    const float* __restrict__ bias, __bf16* __restrict__ Oh,
    const float* __restrict__ Hin,          // MODE1: x;  MODE2: Sprev
    const float2* __restrict__ stats,       // MODE2: per-row {mean, inv}
    const float* __restrict__ lnw, const float* __restrict__ lnb,  // MODE2
    float* __restrict__ Sout) {
  __shared__ __bf16 smem[3 * GBUF];        // 144 KB

  const int tid  = threadIdx.x;
  const int lane = tid & 63;
  const int wv   = tid >> 6;
  const int wm   = wv >> 2;
  const int wn2  = wv & 3;
  const int xcd = blockIdx.x & 7;
  const int kk2 = blockIdx.x >> 3;
  const int tm  = xcd * 4 + (kk2 >> 3);
  const int tn  = kk2 & 7;
  const int rowX = tm * 256, rowW = tn * 128;

  const int lr   = lane & 15;
  const int slot = lane >> 4;

  int offX[4], offW[4];
#pragma unroll
  for (int n = 0; n < 4; ++n) offX[n] = swz_off(wn2 * 64 + n * 16 + lr, slot);
#pragma unroll
  for (int m = 0; m < 4; ++m) offW[m] = GOFF_W + swz_off(wm * 64 + m * 16 + lr, slot);

  f32x4 acc[4][4];
#pragma unroll
  for (int m = 0; m < 4; ++m)
#pragma unroll
    for (int n = 0; n < 4; ++n) acc[m][n] = f32x4{0.f, 0.f, 0.f, 0.f};

  auto stage_tile = [&](int t) {
    __bf16* sb = smem + (t % 3) * GBUF;
    stageR<4>(X,  rowX, t * 64, sb, tid);
    stageR<2>(Wh, rowW, t * 64, sb + GOFF_W, tid);
  };

  auto compute_tile = [&](int t) {
    const __bf16* buf = smem + (t % 3) * GBUF;
#pragma unroll
    for (int kk = 0; kk < 2; ++kk) {
      const int kx = kk * 32;              // elem XOR delta (byte 64)
      bf16_8 xf[4];
#pragma unroll
      for (int n = 0; n < 4; ++n) xf[n] = *(const bf16_8*)&buf[offX[n] ^ kx];
#pragma unroll
      for (int m = 0; m < 4; ++m) {
        const bf16_8 w_h = *(const bf16_8*)&buf[offW[m] ^ kx];
#pragma unroll
        for (int n = 0; n < 4; ++n)
          acc[m][n] = __builtin_amdgcn_mfma_f32_16x16x32_bf16(w_h, xf[n], acc[m][n], 0, 0, 0);
      }
    }
  };

  stage_tile(0); stage_tile(1);
  asm volatile("s_waitcnt vmcnt(6)" ::: "memory");
  __builtin_amdgcn_s_barrier();

#pragma unroll 1
  for (int kt = 0; kt < 14; ++kt) {
    stage_tile(kt + 2);
    compute_tile(kt);
    asm volatile("s_waitcnt vmcnt(6)" ::: "memory");
    __builtin_amdgcn_s_barrier();
  }
  compute_tile(14);
  asm volatile("s_waitcnt vmcnt(0)" ::: "memory");
  __builtin_amdgcn_s_barrier();
  compute_tile(15);

  // epilogue: D reg-quad = 4 consecutive features of one batch row
  const int g4 = slot * 4;
#pragma unroll
  for (int m = 0; m < 4; ++m) {
    const int feat = tn * 128 + wm * 64 + m * 16 + g4;
    const float4 bv = *(const float4*)&bias[feat];
    float4 wq, bq;
    if constexpr (MODE == 2) {
      wq = *(const float4*)&lnw[feat];
      bq = *(const float4*)&lnb[feat];
    }
#pragma unroll
    for (int n = 0; n < 4; ++n) {
      const int nb = tm * 256 + wn2 * 64 + n * 16 + lr;
      const size_t base = (size_t)nb * DIM + feat;
      float v0 = acc[m][n][0] + bv.x;
      float v1 = acc[m][n][1] + bv.y;
      float v2 = acc[m][n][2] + bv.z;
      float v3 = acc[m][n][3] + bv.w;
      if constexpr (MODE == 0) {
        const bf16_4 hv = {(__bf16)fmaxf(v0, 0.f), (__bf16)fmaxf(v1, 0.f),
                           (__bf16)fmaxf(v2, 0.f), (__bf16)fmaxf(v3, 0.f)};
        *(bf16_4*)&Oh[base] = hv;
      } else if constexpr (MODE == 1) {
        const float4 h = *(const float4*)&Hin[base];
        *(float4*)&Sout[base] = float4{v0 + h.x, v1 + h.y, v2 + h.z, v3 + h.w};
      } else {
        const float2 st = stats[nb];                   // {mean, inv}
        const float4 s = *(const float4*)&Hin[base];   // Sprev
        const float h0 = (s.x - st.x) * st.y * wq.x + bq.x;
        const float h1 = (s.y - st.x) * st.y * wq.y + bq.y;
        const float h2 = (s.z - st.x) * st.y * wq.z + bq.z;
        const float h3 = (s.w - st.x) * st.y * wq.w + bq.w;
        *(float4*)&Sout[base] = float4{v0 + h0, v1 + h1, v2 + h2, v3 + h3};
      }
    }
  }
}

// ---------------------------------------------------------------------------
// normcast: per-row stats {mean, inv} + bf16 LN output (next block's X).
// ---------------------------------------------------------------------------
__global__ __launch_bounds__(256) void normcast_kernel(
    const float* __restrict__ S, const float* __restrict__ w,
    const float* __restrict__ b, float2* __restrict__ stats,
    __bf16* __restrict__ phi) {
  const int row = blockIdx.x;
  const int tid = threadIdx.x;
  const int lane = tid & 63;
  const int wv = tid >> 6;
  const float4 v = ((const float4*)(S + (size_t)row * DIM))[tid];

  float s = v.x + v.y + v.z + v.w;
#pragma unroll
  for (int m = 32; m; m >>= 1) s += __shfl_xor(s, m, 64);
  __shared__ float red[8];
  if (lane == 0) red[wv] = s;
  __syncthreads();
  const float mean = (red[0] + red[1] + red[2] + red[3]) * (1.f / DIM);

  const float d0 = v.x - mean, d1 = v.y - mean, d2 = v.z - mean, d3 = v.w - mean;
  float q = d0 * d0 + d1 * d1 + d2 * d2 + d3 * d3;
#pragma unroll
  for (int m = 32; m; m >>= 1) q += __shfl_xor(q, m, 64);
  if (lane == 0) red[4 + wv] = q;
  __syncthreads();
  const float var = (red[4] + red[5] + red[6] + red[7]) * (1.f / DIM);
  const float inv = 1.f / sqrtf(var + EPS);

  if (tid == 0) stats[row] = float2{mean, inv};

  const float4 wv4 = ((const float4*)w)[tid];
  const float4 bv4 = ((const float4*)b)[tid];
  const bf16_4 hv = {(__bf16)(d0 * inv * wv4.x + bv4.x),
                     (__bf16)(d1 * inv * wv4.y + bv4.y),
                     (__bf16)(d2 * inv * wv4.z + bv4.z),
                     (__bf16)(d3 * inv * wv4.w + bv4.w)};
  ((bf16_4*)phi)[(size_t)row * (DIM / 4) + tid] = hv;
}

// ---------------------------------------------------------------------------
// launch
// ---------------------------------------------------------------------------
extern "C" void kernel_launch(void* const* d_in, const int* in_sizes, int n_in,
                              void* d_out, int out_size, void* d_ws, size_t ws_size,
                              hipStream_t stream) {
  const float* x   = (const float*)d_in[0];
  const int*   qw  = (const int*)d_in[1];
  const float* sc  = (const float*)d_in[2];
  const float* bias= (const float*)d_in[3];
  const float* la  = (const float*)d_in[4];
  const float* lb  = (const float*)d_in[5];
  const float* lnw = (const float*)d_in[6];
  const float* lnb = (const float*)d_in[7];
  float* out = (float*)d_out;
  char* ws = (char*)d_ws;

  // ws layout (bytes): WHI 36M | X0 16M | X1 16M | SA 32M | SB 32M | stats 64K
  __bf16* WHI = (__bf16*)(ws);
  __bf16* X0  = (__bf16*)(ws + 37748736);
  __bf16* X1  = (__bf16*)(ws + 54525952);
  float*  SA  = (float*)(ws + 71303168);
  float*  SB  = (float*)(ws + 104857600);
  float2* STT = (float2*)(ws + 138412032);
  (void)ws_size; (void)in_sizes; (void)n_in; (void)out_size;

  xprep_kernel<<<BATCH * DIM / (256 * 4), 256, 0, stream>>>(x, X0);
  wprep_kernel<<<NLAYERS * 128, 256, 0, stream>>>(qw, sc, la, lb, WHI);

  const dim3 ggrid(BATCH / 256 * (DIM / 128));          // 256 = 1 block/CU
  for (int blk = 0; blk < NBLOCKS; ++blk) {
    const int li = blk * 3;
    const size_t w0 = (size_t)li * DIM * DIM;
    const size_t w1 = (size_t)(li + 1) * DIM * DIM;
    const size_t w2 = (size_t)(li + 2) * DIM * DIM;
    float* Scur = (blk & 1) ? SB : SA;
    float* Sprev = (blk & 1) ? SA : SB;

    gemm1_kernel<0><<<ggrid, 512, 0, stream>>>(
        X0, WHI + w0, bias + (size_t)li * DIM, X1,
        nullptr, nullptr, nullptr, nullptr, nullptr);
    gemm1_kernel<0><<<ggrid, 512, 0, stream>>>(
        X1, WHI + w1, bias + (size_t)(li + 1) * DIM, X0,
        nullptr, nullptr, nullptr, nullptr, nullptr);
    float* sout = (blk == NBLOCKS - 1) ? out : Scur;
    if (blk == 0) {
      gemm1_kernel<1><<<ggrid, 512, 0, stream>>>(
          X0, WHI + w2, bias + (size_t)(li + 2) * DIM, nullptr,
          x, nullptr, nullptr, nullptr, sout);
    } else {
      gemm1_kernel<2><<<ggrid, 512, 0, stream>>>(
          X0, WHI + w2, bias + (size_t)(li + 2) * DIM, nullptr,
          Sprev, STT, lnw + (size_t)(blk - 1) * DIM, lnb + (size_t)(blk - 1) * DIM,
          sout);
    }
    if (blk < NBLOCKS - 1) {
      normcast_kernel<<<BATCH, 256, 0, stream>>>(
          Scur, lnw + (size_t)blk * DIM, lnb + (size_t)blk * DIM, STT, X0);
    }
  }
}